// Round 5
// baseline (201.884 us; speedup 1.0000x reference)
//
#include <hip/hip_runtime.h>

#define HW    256
#define PLANE (256*256)
#define L     320     // 5 frames * 64 positions
#define NP    160     // key pairs
#define MID   2
#define NF    5
#define NW    8       // waves per block
#define PPW   20      // key-pairs per wave (8-way split)

typedef float v2f __attribute__((ext_vector_type(2)));

// raw hardware exp2 (v_exp_f32); ~1 ulp, fine vs 27.5 absmax threshold
__device__ __forceinline__ float hw_exp2(float x) {
#if __has_builtin(__builtin_amdgcn_exp2f)
    return __builtin_amdgcn_exp2f(x);
#else
    float r;
    asm("v_exp_f32 %0, %1" : "=v"(r) : "v"(x));
    return r;
#endif
}

__global__ __launch_bounds__(512, 6) void attn_patch_kernel(
    const float* __restrict__ in,        // (1,5,3,256,256)
    const float* __restrict__ outp,      // (1,5,3,256,256)
    const float* __restrict__ Wq,        // (3,3) row-major
    const float* __restrict__ Wk,
    const float* __restrict__ bq,
    const float* __restrict__ bk,
    const float* __restrict__ bv,
    const float* __restrict__ loss_diff, // scalar
    const int*   __restrict__ step,      // scalar
    const int*   __restrict__ max_steps, // scalar
    float* __restrict__ d_out)           // [0]=loss, [1..196608]=rec_image
{
    // pair-planar k/v layout: one b128 = two keys' worth of components,
    // already in the {a,b} register-pair shape v_pk_* wants.
    __shared__ float4 A[NP];             // {kax, kbx, kay, kby}
    __shared__ float4 B[NP];             // {kaz, kbz, vax, vbx}
    __shared__ float4 C[NP];             // {vay, vby, vaz, vbz}
    __shared__ float4 red[NW - 1][NF][64]; // waves 1..7 partials

    const int tid = threadIdx.x;     // 0..511
    const int w   = tid >> 6;        // wave 0..7
    const int l   = tid & 63;        // lane = position within patch
    const int r   = blockIdx.x;      // patch id
    const int s1  = r >> 5, s2 = r & 31;

    const float bv0 = bv[0], bv1 = bv[1], bv2 = bv[2];

    // ---- staging: thread t < 160 builds key pair (2t, 2t+1) ----
    if (tid < NP) {
        const int m0 = 2 * tid;
        const int n  = m0 >> 6, i = m0 & 63;
        const int ph = i >> 3, pw = i & 7;           // pw is even
        const int pix = (s1 * 8 + ph) * HW + s2 * 8 + pw;
        const float2 x0p = *(const float2*)&in[(n * 3 + 0) * PLANE + pix];
        const float2 x1p = *(const float2*)&in[(n * 3 + 1) * PLANE + pix];
        const float2 x2p = *(const float2*)&in[(n * 3 + 2) * PLANE + pix];
        const float ka0 = x0p.x * Wk[0] + x1p.x * Wk[1] + x2p.x * Wk[2] + bk[0];
        const float ka1 = x0p.x * Wk[3] + x1p.x * Wk[4] + x2p.x * Wk[5] + bk[1];
        const float ka2 = x0p.x * Wk[6] + x1p.x * Wk[7] + x2p.x * Wk[8] + bk[2];
        const float kb0 = x0p.y * Wk[0] + x1p.y * Wk[1] + x2p.y * Wk[2] + bk[0];
        const float kb1 = x0p.y * Wk[3] + x1p.y * Wk[4] + x2p.y * Wk[5] + bk[1];
        const float kb2 = x0p.y * Wk[6] + x1p.y * Wk[7] + x2p.y * Wk[8] + bk[2];
        A[tid] = make_float4(ka0, kb0, ka1, kb1);
        B[tid] = make_float4(ka2, kb2, x0p.x + bv0, x0p.y + bv0);
        C[tid] = make_float4(x1p.x + bv1, x1p.y + bv1, x2p.x + bv2, x2p.y + bv2);
    }
    __syncthreads();

    // ---- per-lane queries (x recovered from staged v) ----
    const float QS = 0.57735026918962576f * 1.44269504088896340f; // 1/sqrt(3)*log2(e)
    float q0s[NF], q1s[NF], q2s[NF];
#pragma unroll
    for (int n = 0; n < NF; ++n) {
        const int m  = n * 64 + l;
        const int mm = m >> 1, h = m & 1;
        const float4 b4 = B[mm];
        const float4 c4 = C[mm];
        const float x0 = (h ? b4.w : b4.z) - bv0;
        const float x1 = (h ? c4.y : c4.x) - bv1;
        const float x2 = (h ? c4.w : c4.z) - bv2;
        q0s[n] = (x0 * Wq[0] + x1 * Wq[1] + x2 * Wq[2] + bq[0]) * QS;
        q1s[n] = (x0 * Wq[3] + x1 * Wq[4] + x2 * Wq[5] + bq[1]) * QS;
        q2s[n] = (x0 * Wq[6] + x1 * Wq[7] + x2 * Wq[8] + bq[2]) * QS;
    }

    // ---- main loop: this wave's 20 key pairs, 5 queries, packed fp32 ----
    v2f den2[NF] = {};
    v2f acc2[NF][3] = {};
    const int p0 = w * PPW;
#pragma unroll 2
    for (int pp = 0; pp < PPW; ++pp) {
        const float4 a4 = A[p0 + pp];
        const float4 b4 = B[p0 + pp];
        const float4 c4 = C[p0 + pp];
        const v2f kx = (v2f){a4.x, a4.y};
        const v2f ky = (v2f){a4.z, a4.w};
        const v2f kz = (v2f){b4.x, b4.y};
        const v2f vx = (v2f){b4.z, b4.w};
        const v2f vy = (v2f){c4.x, c4.y};
        const v2f vz = (v2f){c4.z, c4.w};
#pragma unroll
        for (int j = 0; j < NF; ++j) {
            v2f s = kx * (v2f){q0s[j], q0s[j]};
            s = __builtin_elementwise_fma(ky, (v2f){q1s[j], q1s[j]}, s);
            s = __builtin_elementwise_fma(kz, (v2f){q2s[j], q2s[j]}, s);
            v2f p;
            p.x = hw_exp2(s.x);
            p.y = hw_exp2(s.y);
            den2[j] += p;
            acc2[j][0] = __builtin_elementwise_fma(p, vx, acc2[j][0]);
            acc2[j][1] = __builtin_elementwise_fma(p, vy, acc2[j][1]);
            acc2[j][2] = __builtin_elementwise_fma(p, vz, acc2[j][2]);
        }
    }

    // ---- cross-wave reduction: waves 1-7 publish summed halves ----
    if (w > 0) {
#pragma unroll
        for (int j = 0; j < NF; ++j)
            red[w - 1][j][l] = make_float4(acc2[j][0].x + acc2[j][0].y,
                                           acc2[j][1].x + acc2[j][1].y,
                                           acc2[j][2].x + acc2[j][2].y,
                                           den2[j].x + den2[j].y);
    }
    __syncthreads();
    if (w == 0) {
        float den[NF], acc[NF][3];
#pragma unroll
        for (int j = 0; j < NF; ++j) {
            den[j]    = den2[j].x + den2[j].y;
            acc[j][0] = acc2[j][0].x + acc2[j][0].y;
            acc[j][1] = acc2[j][1].x + acc2[j][1].y;
            acc[j][2] = acc2[j][2].x + acc2[j][2].y;
#pragma unroll
            for (int ww = 0; ww < NW - 1; ++ww) {
                const float4 p = red[ww][j][l];
                acc[j][0] += p.x; acc[j][1] += p.y; acc[j][2] += p.z; den[j] += p.w;
            }
        }

        // ---- epilogue (wave 0 only): outputs, losses, rec image ----
        const int pix = (s1 * 8 + (l >> 3)) * HW + s2 * 8 + (l & 7);
        float o[NF][3];
#pragma unroll
        for (int j = 0; j < NF; ++j) {
            const float inv = 1.0f / den[j];
            o[j][0] = acc[j][0] * inv;
            o[j][1] = acc[j][1] * inv;
            o[j][2] = acc[j][2] * inv;
        }

        float y[NF][3];
#pragma unroll
        for (int j = 0; j < NF; ++j)
#pragma unroll
            for (int c = 0; c < 3; ++c)
                y[j][c] = outp[(j * 3 + c) * PLANE + pix];

        const float t  = 1.0f - (float)step[0] / (float)max_steps[0];
        const float t2 = t * t, t4 = t2 * t2, t8 = t4 * t4;
        const float coeff = loss_diff[0] * t8 * t2;

        float midp = 0.0f, allp = 0.0f;
#pragma unroll
        for (int j = 0; j < NF; ++j)
#pragma unroll
            for (int c = 0; c < 3; ++c) {
                const float d = y[MID][c] - o[j][c];
                const float e = y[j][c]   - o[j][c];
                midp += d * d;
                allp += e * e;
            }
        float tl = (midp + coeff * allp) * (1.0f / 960.0f);

#pragma unroll
        for (int c = 0; c < 3; ++c) {
            const float rec = 0.2f * (o[0][c] + o[1][c] + o[2][c] + o[3][c] + o[4][c]);
            d_out[1 + c * PLANE + pix] = rec;
            const float dr = y[MID][c] - rec;
            tl += dr * dr * (1.0f / 196608.0f);
        }

#pragma unroll
        for (int off = 32; off; off >>= 1) tl += __shfl_down(tl, off);
        if (l == 0) atomicAdd(d_out, tl);
    }
}

extern "C" void kernel_launch(void* const* d_in, const int* in_sizes, int n_in,
                              void* d_out, int out_size, void* d_ws, size_t ws_size,
                              hipStream_t stream) {
    const float* in        = (const float*)d_in[0];
    const float* outp      = (const float*)d_in[1];
    const float* Wq        = (const float*)d_in[2];
    const float* Wk        = (const float*)d_in[3];
    const float* bq        = (const float*)d_in[4];
    const float* bk        = (const float*)d_in[5];
    const float* bv        = (const float*)d_in[6];
    const float* loss_diff = (const float*)d_in[7];
    const int*   step      = (const int*)d_in[8];
    const int*   max_steps = (const int*)d_in[9];
    float* out = (float*)d_out;

    // loss accumulator must start at 0 (d_out is poisoned before each call)
    hipMemsetAsync(out, 0, sizeof(float), stream);

    attn_patch_kernel<<<1024, 512, 0, stream>>>(
        in, outp, Wq, Wk, bq, bk, bv, loss_diff, step, max_steps, out);
}

// Round 6
// 160.962 us; speedup vs baseline: 1.2542x; 1.2542x over previous
//
#include <hip/hip_runtime.h>

#define HW    256
#define PLANE (256*256)
#define MID   2
#define NF    5
#define NPB   80     // key-pairs per block (2 blocks per patch)
#define PPW   20     // key-pairs per wave (4 waves per block)

typedef float v2f __attribute__((ext_vector_type(2)));

// raw hardware exp2 (v_exp_f32); ~1 ulp, fine vs 27.5 absmax threshold
__device__ __forceinline__ float hw_exp2(float x) {
#if __has_builtin(__builtin_amdgcn_exp2f)
    return __builtin_amdgcn_exp2f(x);
#else
    float r;
    asm("v_exp_f32 %0, %1" : "=v"(r) : "v"(x));
    return r;
#endif
}

// Kernel 1: per (patch, key-half) partial softmax sums.
// ws layout: float4 ws[2048][NF][64] : (acc0,acc1,acc2,den) per (block, frame, lane/pos)
__global__ __launch_bounds__(256, 7) void attn_partial_kernel(
    const float* __restrict__ in,        // (1,5,3,256,256)
    const float* __restrict__ Wq,
    const float* __restrict__ Wk,
    const float* __restrict__ bq,
    const float* __restrict__ bk,
    const float* __restrict__ bv,
    float4* __restrict__ ws)
{
    __shared__ float4 A[NPB];            // {kax, kbx, kay, kby}
    __shared__ float4 B[NPB];            // {kaz, kbz, vax, vbx}
    __shared__ float4 C[NPB];            // {vay, vby, vaz, vbz}
    __shared__ float4 red[3][NF][64];    // waves 1..3 partials

    const int tid = threadIdx.x;     // 0..255
    const int w   = tid >> 6;        // wave 0..3
    const int l   = tid & 63;        // lane = position within patch
    const int rb  = blockIdx.x;      // 0..2047
    const int r   = rb >> 1;         // patch id
    const int h   = rb & 1;          // key half
    const int s1  = r >> 5, s2 = r & 31;

    const float bv0 = bv[0], bv1 = bv[1], bv2 = bv[2];

    // ---- stage this block's 80 key-pairs (keys [160h, 160h+160)) ----
    if (tid < NPB) {
        const int m0 = 2 * (h * NPB + tid);
        const int n  = m0 >> 6, i = m0 & 63;
        const int ph = i >> 3, pw = i & 7;           // pw is even
        const int pixp = (s1 * 8 + ph) * HW + s2 * 8 + pw;
        const float2 x0p = *(const float2*)&in[(n * 3 + 0) * PLANE + pixp];
        const float2 x1p = *(const float2*)&in[(n * 3 + 1) * PLANE + pixp];
        const float2 x2p = *(const float2*)&in[(n * 3 + 2) * PLANE + pixp];
        const float ka0 = x0p.x * Wk[0] + x1p.x * Wk[1] + x2p.x * Wk[2] + bk[0];
        const float ka1 = x0p.x * Wk[3] + x1p.x * Wk[4] + x2p.x * Wk[5] + bk[1];
        const float ka2 = x0p.x * Wk[6] + x1p.x * Wk[7] + x2p.x * Wk[8] + bk[2];
        const float kb0 = x0p.y * Wk[0] + x1p.y * Wk[1] + x2p.y * Wk[2] + bk[0];
        const float kb1 = x0p.y * Wk[3] + x1p.y * Wk[4] + x2p.y * Wk[5] + bk[1];
        const float kb2 = x0p.y * Wk[6] + x1p.y * Wk[7] + x2p.y * Wk[8] + bk[2];
        A[tid] = make_float4(ka0, kb0, ka1, kb1);
        B[tid] = make_float4(ka2, kb2, x0p.x + bv0, x0p.y + bv0);
        C[tid] = make_float4(x1p.x + bv1, x1p.y + bv1, x2p.x + bv2, x2p.y + bv2);
    }

    // ---- q projection from global (overlaps staging; L1-warm across waves) ----
    const float QS = 0.57735026918962576f * 1.44269504088896340f; // 1/sqrt(3)*log2e
    const int pix = (s1 * 8 + (l >> 3)) * HW + s2 * 8 + (l & 7);
    float q0s[NF], q1s[NF], q2s[NF];
#pragma unroll
    for (int n = 0; n < NF; ++n) {
        const float x0 = in[(n * 3 + 0) * PLANE + pix];
        const float x1 = in[(n * 3 + 1) * PLANE + pix];
        const float x2 = in[(n * 3 + 2) * PLANE + pix];
        q0s[n] = (x0 * Wq[0] + x1 * Wq[1] + x2 * Wq[2] + bq[0]) * QS;
        q1s[n] = (x0 * Wq[3] + x1 * Wq[4] + x2 * Wq[5] + bq[1]) * QS;
        q2s[n] = (x0 * Wq[6] + x1 * Wq[7] + x2 * Wq[8] + bq[2]) * QS;
    }
    __syncthreads();

    // ---- main loop: this wave's 20 key pairs, 5 frames ----
    // packed-fp32 scores, scalar accumulators (keeps VGPR < 64 -> 7 waves/EU)
    float den[NF] = {};
    float acc[NF][3] = {};
    const int p0 = w * PPW;
#pragma unroll 1
    for (int pp = 0; pp < PPW; ++pp) {
        const float4 a4 = A[p0 + pp];
        const float4 b4 = B[p0 + pp];
        const float4 c4 = C[p0 + pp];
        const v2f kx = (v2f){a4.x, a4.y};
        const v2f ky = (v2f){a4.z, a4.w};
        const v2f kz = (v2f){b4.x, b4.y};
#pragma unroll
        for (int j = 0; j < NF; ++j) {
            v2f s = kx * (v2f){q0s[j], q0s[j]};
            s = __builtin_elementwise_fma(ky, (v2f){q1s[j], q1s[j]}, s);
            s = __builtin_elementwise_fma(kz, (v2f){q2s[j], q2s[j]}, s);
            const float pa = hw_exp2(s.x);
            const float pb = hw_exp2(s.y);
            den[j]    += pa + pb;
            acc[j][0] += pa * b4.z;  acc[j][0] += pb * b4.w;
            acc[j][1] += pa * c4.x;  acc[j][1] += pb * c4.y;
            acc[j][2] += pa * c4.z;  acc[j][2] += pb * c4.w;
        }
    }

    // ---- in-block reduction: waves 1-3 publish, wave 0 sums + stores ----
    if (w > 0) {
#pragma unroll
        for (int j = 0; j < NF; ++j)
            red[w - 1][j][l] = make_float4(acc[j][0], acc[j][1], acc[j][2], den[j]);
    }
    __syncthreads();
    if (w == 0) {
#pragma unroll
        for (int j = 0; j < NF; ++j) {
            float a0 = acc[j][0], a1 = acc[j][1], a2 = acc[j][2], d = den[j];
#pragma unroll
            for (int ww = 0; ww < 3; ++ww) {
                const float4 p = red[ww][j][l];
                a0 += p.x; a1 += p.y; a2 += p.z; d += p.w;
            }
            ws[(rb * NF + j) * 64 + l] = make_float4(a0, a1, a2, d);  // coalesced
        }
    }
}

// Kernel 2: combine halves, compute outputs, losses, rec image.
__global__ __launch_bounds__(256) void finalize_kernel(
    const float* __restrict__ outp,
    const float* __restrict__ loss_diff,
    const int*   __restrict__ step,
    const int*   __restrict__ max_steps,
    const float4* __restrict__ ws,
    float* __restrict__ d_out)           // [0]=loss, [1..196608]=rec_image
{
    const int tid = threadIdx.x;
    const int w   = tid >> 6;
    const int l   = tid & 63;
    const int r   = blockIdx.x * 4 + w;  // grid 256 -> patches 0..1023
    const int s1  = r >> 5, s2 = r & 31;
    const int pix = (s1 * 8 + (l >> 3)) * HW + s2 * 8 + (l & 7);

    float o[NF][3];
#pragma unroll
    for (int j = 0; j < NF; ++j) {
        const float4 pa = ws[((2 * r)     * NF + j) * 64 + l];
        const float4 pb = ws[((2 * r + 1) * NF + j) * 64 + l];
        const float inv = 1.0f / (pa.w + pb.w);
        o[j][0] = (pa.x + pb.x) * inv;
        o[j][1] = (pa.y + pb.y) * inv;
        o[j][2] = (pa.z + pb.z) * inv;
    }

    float y[NF][3];
#pragma unroll
    for (int j = 0; j < NF; ++j)
#pragma unroll
        for (int c = 0; c < 3; ++c)
            y[j][c] = outp[(j * 3 + c) * PLANE + pix];

    const float t  = 1.0f - (float)step[0] / (float)max_steps[0];
    const float t2 = t * t, t4 = t2 * t2, t8 = t4 * t4;
    const float coeff = loss_diff[0] * t8 * t2;

    float midp = 0.0f, allp = 0.0f;
#pragma unroll
    for (int j = 0; j < NF; ++j)
#pragma unroll
        for (int c = 0; c < 3; ++c) {
            const float d = y[MID][c] - o[j][c];
            const float e = y[j][c]   - o[j][c];
            midp += d * d;
            allp += e * e;
        }
    float tl = (midp + coeff * allp) * (1.0f / 960.0f);

#pragma unroll
    for (int c = 0; c < 3; ++c) {
        const float rec = 0.2f * (o[0][c] + o[1][c] + o[2][c] + o[3][c] + o[4][c]);
        d_out[1 + c * PLANE + pix] = rec;
        const float dr = y[MID][c] - rec;
        tl += dr * dr * (1.0f / 196608.0f);
    }

#pragma unroll
    for (int off = 32; off; off >>= 1) tl += __shfl_down(tl, off);
    if (l == 0) atomicAdd(d_out, tl);
}

extern "C" void kernel_launch(void* const* d_in, const int* in_sizes, int n_in,
                              void* d_out, int out_size, void* d_ws, size_t ws_size,
                              hipStream_t stream) {
    const float* in        = (const float*)d_in[0];
    const float* outp      = (const float*)d_in[1];
    const float* Wq        = (const float*)d_in[2];
    const float* Wk        = (const float*)d_in[3];
    const float* bq        = (const float*)d_in[4];
    const float* bk        = (const float*)d_in[5];
    const float* bv        = (const float*)d_in[6];
    const float* loss_diff = (const float*)d_in[7];
    const int*   step      = (const int*)d_in[8];
    const int*   max_steps = (const int*)d_in[9];
    float*  out = (float*)d_out;
    float4* ws  = (float4*)d_ws;   // 2048*5*64*16 B = 10.5 MB, fully overwritten each call

    // loss accumulator must start at 0 (d_out is poisoned before each call)
    hipMemsetAsync(out, 0, sizeof(float), stream);

    attn_partial_kernel<<<2048, 256, 0, stream>>>(in, Wq, Wk, bq, bk, bv, ws);
    finalize_kernel<<<256, 256, 0, stream>>>(outp, loss_diff, step, max_steps, ws, out);
}

// Round 7
// 126.831 us; speedup vs baseline: 1.5918x; 1.2691x over previous
//
#include <hip/hip_runtime.h>

#define HW    256
#define PLANE (256*256)
#define MID   2
#define NF    5
#define PPW   20     // key-pairs per wave; 8 waves (4 blocks x 2) per patch

typedef float v2f __attribute__((ext_vector_type(2)));

// raw hardware exp2 (v_exp_f32); ~1 ulp, fine vs 27.5 absmax threshold
__device__ __forceinline__ float hw_exp2(float x) {
#if __has_builtin(__builtin_amdgcn_exp2f)
    return __builtin_amdgcn_exp2f(x);
#else
    float r;
    asm("v_exp_f32 %0, %1" : "=v"(r) : "v"(x));
    return r;
#endif
}

// Kernel 1: per (patch, key-quarter) partial softmax sums.
// Block = 128 thr = 2 waves; wave w owns pairs [qt*40 + w*20, +20) of its patch.
// Each wave stages its own LDS slice -> no barrier before the main loop.
// ws layout: float4 ws[(patch*4+qt)*NF + j][64] : (acc0,acc1,acc2,den)
__global__ __launch_bounds__(128) void attn_partial_kernel(
    const float* __restrict__ in,        // (1,5,3,256,256)
    const float* __restrict__ Wq,
    const float* __restrict__ Wk,
    const float* __restrict__ bq,
    const float* __restrict__ bk,
    const float* __restrict__ bv,
    float4* __restrict__ ws)
{
    __shared__ float4 KV[2 * PPW][3];    // per pair: {kax,kbx,kay,kby},{kaz,kbz,vax,vbx},{vay,vby,vaz,vbz}
    __shared__ float4 red[NF][64];       // wave-1 partials for end combine

    const int tid = threadIdx.x;         // 0..127
    const int w   = tid >> 6;            // wave 0..1
    const int l   = tid & 63;            // lane = position within patch
    const int b   = blockIdx.x;          // 0..4095
    const int r   = b >> 2;              // patch id
    const int qt  = b & 3;               // key quarter
    const int s1  = r >> 5, s2 = r & 31;

    const float bv0 = bv[0], bv1 = bv[1], bv2 = bv[2];

    // ---- staging: lanes 0..19 of each wave build this wave's 20 key pairs ----
    if (l < PPW) {
        const int p  = qt * 40 + w * PPW + l;    // global pair idx 0..159
        const int m0 = 2 * p;
        const int n  = m0 >> 6, i = m0 & 63;
        const int ph = i >> 3, pw = i & 7;       // pw even
        const int pixp = (s1 * 8 + ph) * HW + s2 * 8 + pw;
        const float2 x0p = *(const float2*)&in[(n * 3 + 0) * PLANE + pixp];
        const float2 x1p = *(const float2*)&in[(n * 3 + 1) * PLANE + pixp];
        const float2 x2p = *(const float2*)&in[(n * 3 + 2) * PLANE + pixp];
        const float ka0 = x0p.x * Wk[0] + x1p.x * Wk[1] + x2p.x * Wk[2] + bk[0];
        const float ka1 = x0p.x * Wk[3] + x1p.x * Wk[4] + x2p.x * Wk[5] + bk[1];
        const float ka2 = x0p.x * Wk[6] + x1p.x * Wk[7] + x2p.x * Wk[8] + bk[2];
        const float kb0 = x0p.y * Wk[0] + x1p.y * Wk[1] + x2p.y * Wk[2] + bk[0];
        const float kb1 = x0p.y * Wk[3] + x1p.y * Wk[4] + x2p.y * Wk[5] + bk[1];
        const float kb2 = x0p.y * Wk[6] + x1p.y * Wk[7] + x2p.y * Wk[8] + bk[2];
        const int s = w * PPW + l;
        KV[s][0] = make_float4(ka0, kb0, ka1, kb1);
        KV[s][1] = make_float4(ka2, kb2, x0p.x + bv0, x0p.y + bv0);
        KV[s][2] = make_float4(x1p.x + bv1, x1p.y + bv1, x2p.x + bv2, x2p.y + bv2);
    }

    // ---- q projection (overlaps staging latency); stored as v2f splats ----
    const float QS = 0.57735026918962576f * 1.44269504088896340f; // 1/sqrt(3)*log2e
    const int pix = (s1 * 8 + (l >> 3)) * HW + s2 * 8 + (l & 7);
    v2f qx[NF], qy[NF], qz[NF];
#pragma unroll
    for (int n = 0; n < NF; ++n) {
        const float x0 = in[(n * 3 + 0) * PLANE + pix];
        const float x1 = in[(n * 3 + 1) * PLANE + pix];
        const float x2 = in[(n * 3 + 2) * PLANE + pix];
        const float q0 = (x0 * Wq[0] + x1 * Wq[1] + x2 * Wq[2] + bq[0]) * QS;
        const float q1 = (x0 * Wq[3] + x1 * Wq[4] + x2 * Wq[5] + bq[1]) * QS;
        const float q2 = (x0 * Wq[6] + x1 * Wq[7] + x2 * Wq[8] + bq[2]) * QS;
        qx[n] = (v2f){q0, q0};
        qy[n] = (v2f){q1, q1};
        qz[n] = (v2f){q2, q2};
    }
    // wave-private LDS slice: no __syncthreads needed (in-wave ordering only)

    // ---- main loop: 20 pairs, 5 frames, packed fp32 ----
    v2f den2[NF] = {};
    v2f acc2[NF][3] = {};
    const int base = w * PPW;
#pragma unroll 2
    for (int pp = 0; pp < PPW; ++pp) {
        const float4 a4 = KV[base + pp][0];
        const float4 b4 = KV[base + pp][1];
        const float4 c4 = KV[base + pp][2];
        const v2f kx = (v2f){a4.x, a4.y};
        const v2f ky = (v2f){a4.z, a4.w};
        const v2f kz = (v2f){b4.x, b4.y};
        const v2f vx = (v2f){b4.z, b4.w};
        const v2f vy = (v2f){c4.x, c4.y};
        const v2f vz = (v2f){c4.z, c4.w};
#pragma unroll
        for (int j = 0; j < NF; ++j) {
            v2f s = kx * qx[j];
            s = __builtin_elementwise_fma(ky, qy[j], s);
            s = __builtin_elementwise_fma(kz, qz[j], s);
            v2f p;
            p.x = hw_exp2(s.x);
            p.y = hw_exp2(s.y);
            den2[j] += p;
            acc2[j][0] = __builtin_elementwise_fma(p, vx, acc2[j][0]);
            acc2[j][1] = __builtin_elementwise_fma(p, vy, acc2[j][1]);
            acc2[j][2] = __builtin_elementwise_fma(p, vz, acc2[j][2]);
        }
    }

    // ---- end combine: wave 1 publishes, wave 0 adds and stores to ws ----
    if (w == 1) {
#pragma unroll
        for (int j = 0; j < NF; ++j)
            red[j][l] = make_float4(acc2[j][0].x + acc2[j][0].y,
                                    acc2[j][1].x + acc2[j][1].y,
                                    acc2[j][2].x + acc2[j][2].y,
                                    den2[j].x + den2[j].y);
    }
    __syncthreads();
    if (w == 0) {
#pragma unroll
        for (int j = 0; j < NF; ++j) {
            const float4 p = red[j][l];
            ws[(b * NF + j) * 64 + l] = make_float4(
                acc2[j][0].x + acc2[j][0].y + p.x,
                acc2[j][1].x + acc2[j][1].y + p.y,
                acc2[j][2].x + acc2[j][2].y + p.z,
                den2[j].x + den2[j].y + p.w);
        }
    }
}

// Kernel 2: combine the 4 quarter-partials, outputs, losses, rec image.
__global__ __launch_bounds__(256) void finalize_kernel(
    const float* __restrict__ outp,
    const float* __restrict__ loss_diff,
    const int*   __restrict__ step,
    const int*   __restrict__ max_steps,
    const float4* __restrict__ ws,
    float* __restrict__ d_out)           // [0]=loss, [1..196608]=rec_image
{
    const int tid = threadIdx.x;
    const int w   = tid >> 6;
    const int l   = tid & 63;
    const int r   = blockIdx.x * 4 + w;  // grid 256 -> patches 0..1023
    const int s1  = r >> 5, s2 = r & 31;
    const int pix = (s1 * 8 + (l >> 3)) * HW + s2 * 8 + (l & 7);

    float o[NF][3];
#pragma unroll
    for (int j = 0; j < NF; ++j) {
        float a0 = 0, a1 = 0, a2 = 0, d = 0;
#pragma unroll
        for (int qt = 0; qt < 4; ++qt) {
            const float4 p = ws[((r * 4 + qt) * NF + j) * 64 + l];
            a0 += p.x; a1 += p.y; a2 += p.z; d += p.w;
        }
        const float inv = 1.0f / d;
        o[j][0] = a0 * inv; o[j][1] = a1 * inv; o[j][2] = a2 * inv;
    }

    float y[NF][3];
#pragma unroll
    for (int j = 0; j < NF; ++j)
#pragma unroll
        for (int c = 0; c < 3; ++c)
            y[j][c] = outp[(j * 3 + c) * PLANE + pix];

    const float t  = 1.0f - (float)step[0] / (float)max_steps[0];
    const float t2 = t * t, t4 = t2 * t2, t8 = t4 * t4;
    const float coeff = loss_diff[0] * t8 * t2;

    float midp = 0.0f, allp = 0.0f;
#pragma unroll
    for (int j = 0; j < NF; ++j)
#pragma unroll
        for (int c = 0; c < 3; ++c) {
            const float d = y[MID][c] - o[j][c];
            const float e = y[j][c]   - o[j][c];
            midp += d * d;
            allp += e * e;
        }
    float tl = (midp + coeff * allp) * (1.0f / 960.0f);

#pragma unroll
    for (int c = 0; c < 3; ++c) {
        const float rec = 0.2f * (o[0][c] + o[1][c] + o[2][c] + o[3][c] + o[4][c]);
        d_out[1 + c * PLANE + pix] = rec;
        const float dr = y[MID][c] - rec;
        tl += dr * dr * (1.0f / 196608.0f);
    }

#pragma unroll
    for (int off = 32; off; off >>= 1) tl += __shfl_down(tl, off);
    if (l == 0) atomicAdd(d_out, tl);
}

extern "C" void kernel_launch(void* const* d_in, const int* in_sizes, int n_in,
                              void* d_out, int out_size, void* d_ws, size_t ws_size,
                              hipStream_t stream) {
    const float* in        = (const float*)d_in[0];
    const float* outp      = (const float*)d_in[1];
    const float* Wq        = (const float*)d_in[2];
    const float* Wk        = (const float*)d_in[3];
    const float* bq        = (const float*)d_in[4];
    const float* bk        = (const float*)d_in[5];
    const float* bv        = (const float*)d_in[6];
    const float* loss_diff = (const float*)d_in[7];
    const int*   step      = (const int*)d_in[8];
    const int*   max_steps = (const int*)d_in[9];
    float*  out = (float*)d_out;
    float4* ws  = (float4*)d_ws;   // 4096*5*64*16 B = 21 MB, fully overwritten each call

    // loss accumulator must start at 0 (d_out is poisoned before each call)
    hipMemsetAsync(out, 0, sizeof(float), stream);

    attn_partial_kernel<<<4096, 128, 0, stream>>>(in, Wq, Wk, bq, bk, bv, ws);
    finalize_kernel<<<256, 256, 0, stream>>>(outp, loss_diff, step, max_steps, ws, out);
}

// Round 8
// 100.139 us; speedup vs baseline: 2.0160x; 1.2665x over previous
//
#include <hip/hip_runtime.h>

#define HW    256
#define PLANE (256*256)
#define MID   2
#define NF    5
#define VTS   328     // Vt row stride in shorts (+8 pad: breaks 16-way bank alias)

typedef float f32x4 __attribute__((ext_vector_type(4)));
typedef short s16x8 __attribute__((ext_vector_type(8)));

__device__ __forceinline__ float hw_exp2(float x) {
#if __has_builtin(__builtin_amdgcn_exp2f)
    return __builtin_amdgcn_exp2f(x);
#else
    float r; asm("v_exp_f32 %0, %1" : "=v"(r) : "v"(x)); return r;
#endif
}

// float -> bf16 bits (RNE), result in low 16 bits
__device__ __forceinline__ unsigned int f2bf(float f) {
    unsigned int u = __float_as_uint(f);
    u += 0x7FFF + ((u >> 16) & 1);
    return u >> 16;
}

__device__ __forceinline__ s16x8 mk_frag4(uint2 lo) {   // 4 bf16 + 4 zeros
    union { s16x8 v; unsigned int u[4]; } c;
    c.u[0] = lo.x; c.u[1] = lo.y; c.u[2] = 0; c.u[3] = 0;
    return c.v;
}
__device__ __forceinline__ s16x8 mk_frag8(unsigned int u0, unsigned int u1,
                                          unsigned int u2, unsigned int u3) {
    union { s16x8 v; unsigned int u[4]; } c;
    c.u[0] = u0; c.u[1] = u1; c.u[2] = u2; c.u[3] = u3;
    return c.v;
}

// One block (4 waves) per patch. Wave w owns query-tiles w*5..w*5+4 (16 q each).
// Scores: S'[key][query] via mfma(A=K, B=Q'), dim K padded 3->32.
// P = exp2(S') stays in registers (C layout == PV A layout, m=lane&15=query).
// [acc|den] = P * [V | ones] via mfma(A=P, B=Vt-frag), keys contracted 32/step.
__global__ __launch_bounds__(256) void attn_mfma_kernel(
    const float* __restrict__ in,        // (1,5,3,256,256)
    const float* __restrict__ outp,      // (1,5,3,256,256)
    const float* __restrict__ Wq,
    const float* __restrict__ Wk,
    const float* __restrict__ bq,
    const float* __restrict__ bk,
    const float* __restrict__ bv,
    const float* __restrict__ loss_diff,
    const int*   __restrict__ step,
    const int*   __restrict__ max_steps,
    float* __restrict__ d_out)           // [0]=loss, [1..196608]=rec_image
{
    __shared__ __align__(16) unsigned short Kbf[320 * 4]; // [token][dim0..2,0] bf16
    __shared__ __align__(16) unsigned short Qbf[320 * 4];
    __shared__ __align__(16) unsigned short Vt[16 * VTS]; // [ch][token]; ch3=1.0, ch4..15=0
    __shared__ __align__(16) float oLDS[320 * 4];         // [token][acc0,acc1,acc2,den]
    __shared__ float red[4];

    const int tid  = threadIdx.x;    // 0..255
    const int w    = tid >> 6;       // wave 0..3
    const int lane = tid & 63;
    const int col  = lane & 15;      // MFMA n/m index
    const int quad = lane >> 4;
    const int r    = blockIdx.x;     // patch id
    const int s1   = r >> 5, s2 = r & 31;

    // ---- Vt static rows: row 3 = bf16(1.0) pairs, rows 4..15 = 0 ----
    {
        unsigned int* v32 = (unsigned int*)Vt;
        for (int idx = 3 * (VTS / 2) + tid; idx < 16 * (VTS / 2); idx += 256)
            v32[idx] = (idx < 4 * (VTS / 2)) ? 0x3F803F80u : 0u;
    }

    // ---- token staging: K, Q' (scaled), V^T -> bf16 in LDS ----
    const float QS = 0.57735026918962576f * 1.44269504088896340f; // 1/sqrt(3)*log2e
    const float bv0 = bv[0], bv1 = bv[1], bv2 = bv[2];
    for (int t = tid; t < 320; t += 256) {
        const int n = t >> 6, i = t & 63;
        const int pix = (s1 * 8 + (i >> 3)) * HW + s2 * 8 + (i & 7);
        const float x0 = in[(n * 3 + 0) * PLANE + pix];
        const float x1 = in[(n * 3 + 1) * PLANE + pix];
        const float x2 = in[(n * 3 + 2) * PLANE + pix];
        const float k0 = x0 * Wk[0] + x1 * Wk[1] + x2 * Wk[2] + bk[0];
        const float k1 = x0 * Wk[3] + x1 * Wk[4] + x2 * Wk[5] + bk[1];
        const float k2 = x0 * Wk[6] + x1 * Wk[7] + x2 * Wk[8] + bk[2];
        const float q0 = (x0 * Wq[0] + x1 * Wq[1] + x2 * Wq[2] + bq[0]) * QS;
        const float q1 = (x0 * Wq[3] + x1 * Wq[4] + x2 * Wq[5] + bq[1]) * QS;
        const float q2 = (x0 * Wq[6] + x1 * Wq[7] + x2 * Wq[8] + bq[2]) * QS;
        *(uint2*)&Kbf[t * 4] = make_uint2(f2bf(k0) | (f2bf(k1) << 16), f2bf(k2));
        *(uint2*)&Qbf[t * 4] = make_uint2(f2bf(q0) | (f2bf(q1) << 16), f2bf(q2));
        Vt[0 * VTS + t] = (unsigned short)f2bf(x0 + bv0);
        Vt[1 * VTS + t] = (unsigned short)f2bf(x1 + bv1);
        Vt[2 * VTS + t] = (unsigned short)f2bf(x2 + bv2);
    }
    __syncthreads();

    // ---- Q fragments for this wave's 5 query-tiles (dims in quad 0 only) ----
    s16x8 qf[5];
#pragma unroll
    for (int u = 0; u < 5; ++u) {
        uint2 qr = *(const uint2*)&Qbf[((w * 5 + u) * 16 + col) * 4];
        if (quad != 0) { qr.x = 0; qr.y = 0; }
        qf[u] = mk_frag4(qr);
    }

    f32x4 acc[5];
#pragma unroll
    for (int u = 0; u < 5; ++u) acc[u] = (f32x4){0.f, 0.f, 0.f, 0.f};
    const f32x4 zero4 = (f32x4){0.f, 0.f, 0.f, 0.f};

    // ---- main loop over 10 key-blocks of 32 ----
    for (int kb = 0; kb < 10; ++kb) {
        uint2 kr0 = *(const uint2*)&Kbf[(kb * 32 + col) * 4];
        uint2 kr1 = *(const uint2*)&Kbf[(kb * 32 + 16 + col) * 4];
        if (quad != 0) { kr0.x = 0; kr0.y = 0; kr1.x = 0; kr1.y = 0; }
        const s16x8 a0 = mk_frag4(kr0);
        const s16x8 a1 = mk_frag4(kr1);
        // V B-fragment, key permutation matches C->A repack below
        const unsigned short* vp = &Vt[col * VTS + kb * 32 + quad * 4];
        const uint2 vlo = *(const uint2*)vp;          // keys +0..3  -> slots j0..3
        const uint2 vhi = *(const uint2*)(vp + 16);   // keys +16..19 -> slots j4..7
        const s16x8 vf = mk_frag8(vlo.x, vlo.y, vhi.x, vhi.y);
#pragma unroll
        for (int u = 0; u < 5; ++u) {
            f32x4 c0 = __builtin_amdgcn_mfma_f32_16x16x32_bf16(a0, qf[u], zero4, 0, 0, 0);
            f32x4 c1 = __builtin_amdgcn_mfma_f32_16x16x32_bf16(a1, qf[u], zero4, 0, 0, 0);
            // P = exp2(S'), truncate to bf16, pack into PV A-fragment
            const unsigned int p0 = (__float_as_uint(hw_exp2(c0[0])) >> 16) |
                                    (__float_as_uint(hw_exp2(c0[1])) & 0xFFFF0000u);
            const unsigned int p1 = (__float_as_uint(hw_exp2(c0[2])) >> 16) |
                                    (__float_as_uint(hw_exp2(c0[3])) & 0xFFFF0000u);
            const unsigned int p2 = (__float_as_uint(hw_exp2(c1[0])) >> 16) |
                                    (__float_as_uint(hw_exp2(c1[1])) & 0xFFFF0000u);
            const unsigned int p3 = (__float_as_uint(hw_exp2(c1[2])) >> 16) |
                                    (__float_as_uint(hw_exp2(c1[3])) & 0xFFFF0000u);
            const s16x8 pf = mk_frag8(p0, p1, p2, p3);
            acc[u] = __builtin_amdgcn_mfma_f32_16x16x32_bf16(pf, vf, acc[u], 0, 0, 0);
        }
    }

    // ---- write (acc0..2, den) per token to LDS; lane holds D[q=quad*4+rr][ch=col] ----
    if (col < 4) {
#pragma unroll
        for (int u = 0; u < 5; ++u) {
            const int tbase = (w * 5 + u) * 16 + quad * 4;
#pragma unroll
            for (int rr = 0; rr < 4; ++rr)
                oLDS[(tbase + rr) * 4 + col] = acc[u][rr];
        }
    }
    __syncthreads();

    // ---- epilogue: losses + rec image ----
    float tl = 0.0f;
    const float tt = 1.0f - (float)step[0] / (float)max_steps[0];
    const float t2 = tt * tt, t4 = t2 * t2, t8 = t4 * t4;
    const float coeff = loss_diff[0] * t8 * t2;

    for (int t = tid; t < 320; t += 256) {
        const int n = t >> 6, i = t & 63;
        const int pix = (s1 * 8 + (i >> 3)) * HW + s2 * 8 + (i & 7);
        const float4 oa = *(const float4*)&oLDS[t * 4];
        const float inv = 1.0f / oa.w;
        const float o0 = oa.x * inv, o1 = oa.y * inv, o2 = oa.z * inv;
        const float y0  = outp[(n * 3 + 0) * PLANE + pix];
        const float y1  = outp[(n * 3 + 1) * PLANE + pix];
        const float y2  = outp[(n * 3 + 2) * PLANE + pix];
        const float ym0 = outp[(MID * 3 + 0) * PLANE + pix];
        const float ym1 = outp[(MID * 3 + 1) * PLANE + pix];
        const float ym2 = outp[(MID * 3 + 2) * PLANE + pix];
        const float d0 = ym0 - o0, d1 = ym1 - o1, d2 = ym2 - o2;
        const float e0 = y0 - o0,  e1 = y1 - o1,  e2 = y2 - o2;
        tl += (d0*d0 + d1*d1 + d2*d2 + coeff * (e0*e0 + e1*e1 + e2*e2)) * (1.0f / 960.0f);
    }

    if (tid < 192) {
        const int c = tid >> 6, ii = tid & 63;
        const int pix2 = (s1 * 8 + (ii >> 3)) * HW + s2 * 8 + (ii & 7);
        float rec = 0.0f;
#pragma unroll
        for (int n = 0; n < NF; ++n) {
            const int t = n * 64 + ii;
            rec += oLDS[t * 4 + c] / oLDS[t * 4 + 3];
        }
        rec *= 0.2f;
        d_out[1 + c * PLANE + pix2] = rec;
        const float ym = outp[(MID * 3 + c) * PLANE + pix2];
        const float dr = ym - rec;
        tl += dr * dr * (1.0f / 196608.0f);
    }

#pragma unroll
    for (int off = 32; off; off >>= 1) tl += __shfl_down(tl, off);
    if (lane == 0) red[w] = tl;
    __syncthreads();
    if (tid == 0) atomicAdd(d_out, red[0] + red[1] + red[2] + red[3]);
}

extern "C" void kernel_launch(void* const* d_in, const int* in_sizes, int n_in,
                              void* d_out, int out_size, void* d_ws, size_t ws_size,
                              hipStream_t stream) {
    const float* in        = (const float*)d_in[0];
    const float* outp      = (const float*)d_in[1];
    const float* Wq        = (const float*)d_in[2];
    const float* Wk        = (const float*)d_in[3];
    const float* bq        = (const float*)d_in[4];
    const float* bk        = (const float*)d_in[5];
    const float* bv        = (const float*)d_in[6];
    const float* loss_diff = (const float*)d_in[7];
    const int*   step      = (const int*)d_in[8];
    const int*   max_steps = (const int*)d_in[9];
    float* out = (float*)d_out;

    // loss accumulator must start at 0 (d_out is poisoned before each call)
    hipMemsetAsync(out, 0, sizeof(float), stream);

    attn_mfma_kernel<<<1024, 256, 0, stream>>>(
        in, outp, Wq, Wk, bq, bk, bv, loss_diff, step, max_steps, out);
}